// Round 1
// baseline (1465.851 us; speedup 1.0000x reference)
//
#include <hip/hip_runtime.h>
#include <hip/hip_bf16.h>
#include <cstdint>

#define B_   2
#define S_   2048
#define D_   4096
#define NH_  32
#define NKV_ 8
#define HD_  128
#define BS_  (B_*S_)      // 4096 rows
#define NQK_ 6144         // NH*HD + 2*NKV*HD

typedef __bf16 bf16_t;
typedef __bf16 bf16x8 __attribute__((ext_vector_type(8)));
typedef __bf16 bf16x4 __attribute__((ext_vector_type(4)));
typedef __bf16 bf16x2 __attribute__((ext_vector_type(2)));
typedef float  f32x4  __attribute__((ext_vector_type(4)));

typedef const __attribute__((address_space(1))) void* gas_ptr;
typedef __attribute__((address_space(3))) void* las_ptr;

__device__ __forceinline__ void gload_lds16(const void* g, void* l) {
  __builtin_amdgcn_global_load_lds((gas_ptr)g, (las_ptr)l, 16, 0, 0);
}

// ---------------- f32 -> bf16 convert (vectorized) ----------------
__global__ __launch_bounds__(256) void k_cvt(const float4* __restrict__ in,
                                             bf16x4* __restrict__ out, int n4) {
  int i = blockIdx.x * 256 + threadIdx.x;
  if (i >= n4) return;
  float4 v = in[i];
  bf16x4 o = { (bf16_t)v.x, (bf16_t)v.y, (bf16_t)v.z, (bf16_t)v.w };
  out[i] = o;
}

// ---------------- w[K][N] f32 -> wt[N][K] bf16 (tiled transpose) ----------------
__global__ __launch_bounds__(256) void k_transpose_cvt(const float* __restrict__ w,
                                                       bf16_t* __restrict__ wt,
                                                       int K, int N) {
  __shared__ float tile[32][33];
  int n0 = blockIdx.x * 32, k0 = blockIdx.y * 32;
  int tx = threadIdx.x, ty = threadIdx.y;   // 32x8
#pragma unroll
  for (int i = 0; i < 4; i++)
    tile[ty + 8*i][tx] = w[(size_t)(k0 + ty + 8*i) * N + n0 + tx];
  __syncthreads();
#pragma unroll
  for (int i = 0; i < 4; i++)
    wt[(size_t)(n0 + ty + 8*i) * K + k0 + tx] = (bf16_t)tile[tx][ty + 8*i];
}

// ---------------- NT GEMM: C[M][N] = A[M][K] @ Bt[N][K]^T (bf16 in, CT out) -----
// m97 structure: 128x128 tile, BK=32, 4 waves (2x2), 4x4 16x16x32 frags/wave.
template <typename CT>
__global__ __launch_bounds__(256) void k_gemm_bt(const bf16_t* __restrict__ A,
                                                 const bf16_t* __restrict__ Bt,
                                                 CT* __restrict__ C,
                                                 int M, int N, int K) {
  __shared__ __align__(16) bf16_t As[128 * 32];
  __shared__ __align__(16) bf16_t Bs[128 * 32];
  const int tid = threadIdx.x;
  const int l = tid & 63, w = tid >> 6;
  const int lr = l & 15, lg = l >> 4;
  const int wm = w >> 1, wn = w & 1;
  const int bm = blockIdx.y, bn = blockIdx.x;

  const bf16_t* Ab = A  + (size_t)bm * 128 * K;
  const bf16_t* Bb = Bt + (size_t)bn * 128 * K;

  f32x4 acc[4][4];
#pragma unroll
  for (int m = 0; m < 4; m++)
#pragma unroll
    for (int n = 0; n < 4; n++) acc[m][n] = f32x4{0.f, 0.f, 0.f, 0.f};

  const int c0 = tid, c1 = 256 + tid;
  const int r0 = c0 >> 2, q0 = (c0 & 3) * 8;
  const int r1 = c1 >> 2, q1 = (c1 & 3) * 8;

  for (int kt = 0; kt < K; kt += 32) {
    gload_lds16(Ab + (size_t)r0 * K + kt + q0, As + c0 * 8);
    gload_lds16(Ab + (size_t)r1 * K + kt + q1, As + c1 * 8);
    gload_lds16(Bb + (size_t)r0 * K + kt + q0, Bs + c0 * 8);
    gload_lds16(Bb + (size_t)r1 * K + kt + q1, Bs + c1 * 8);
    __syncthreads();
    bf16x8 af[4], bfr[4];
#pragma unroll
    for (int m = 0; m < 4; m++)
      af[m] = *(const bf16x8*)(As + (wm * 64 + m * 16 + lr) * 32 + lg * 8);
#pragma unroll
    for (int n = 0; n < 4; n++)
      bfr[n] = *(const bf16x8*)(Bs + (wn * 64 + n * 16 + lr) * 32 + lg * 8);
#pragma unroll
    for (int m = 0; m < 4; m++)
#pragma unroll
      for (int n = 0; n < 4; n++)
        acc[m][n] = __builtin_amdgcn_mfma_f32_16x16x32_bf16(af[m], bfr[n], acc[m][n], 0, 0, 0);
    __syncthreads();
  }

#pragma unroll
  for (int m = 0; m < 4; m++) {
    int row0 = bm * 128 + wm * 64 + m * 16 + lg * 4;
#pragma unroll
    for (int n = 0; n < 4; n++) {
      int col = bn * 128 + wn * 64 + n * 16 + lr;
#pragma unroll
      for (int i = 0; i < 4; i++) {
        C[(size_t)(row0 + i) * N + col] = (CT)acc[m][n][i];
      }
    }
  }
}

// ---------------- RoPE + head-major reorder ----------------
// src: qkv[BS][NQK] bf16, head h cols at col_off + h*HD. dst: [B][nheads][S][HD].
// Interleaved rope: pairs (2p, 2p+1). mul pre-scales (1/sqrt(HD) for Q).
__global__ __launch_bounds__(256) void k_rope(const bf16_t* __restrict__ qkv,
                                              const float* __restrict__ fcos,
                                              const float* __restrict__ fsin,
                                              bf16_t* __restrict__ dst,
                                              int nheads, int col_off, float mul) {
  int idx = blockIdx.x * 256 + threadIdx.x;   // B*S*nheads*64 threads
  int p = idx & 63;
  int h = (idx >> 6) % nheads;
  int bs = idx / (64 * nheads);
  int s = bs & (S_ - 1);
  int b = bs >> 11;                            // bs / S_
  const bf16_t* src = qkv + (size_t)bs * NQK_ + col_off + h * HD_ + 2 * p;
  bf16x2 ab = *(const bf16x2*)src;
  float a = (float)ab[0], bb = (float)ab[1];
  float c = fcos[s * 64 + p], sn = fsin[s * 64 + p];
  bf16x2 o = { (bf16_t)((a * c - bb * sn) * mul), (bf16_t)((a * sn + bb * c) * mul) };
  *(bf16x2*)(dst + ((((size_t)b * nheads + h) * S_ + s) * HD_) + 2 * p) = o;
}

// ---------------- V transpose: qkv v-cols -> vt[B][NKV][HD][S] ----------------
__global__ __launch_bounds__(256) void k_vtrans(const bf16_t* __restrict__ qkv,
                                                bf16_t* __restrict__ vtr) {
  __shared__ bf16_t tile[32][33];
  int s0 = blockIdx.x * 32, d0 = blockIdx.y * 32, z = blockIdx.z;  // z = b*NKV+kvh
  int b = z >> 3, kvh = z & 7;
  int tx = threadIdx.x, ty = threadIdx.y;
#pragma unroll
  for (int i = 0; i < 4; i++)
    tile[ty + 8*i][tx] =
        qkv[(size_t)(b * S_ + s0 + ty + 8*i) * NQK_ + (D_ + NKV_ * HD_) + kvh * HD_ + d0 + tx];
  __syncthreads();
#pragma unroll
  for (int i = 0; i < 4; i++)
    vtr[((size_t)z * HD_ + d0 + ty + 8*i) * S_ + s0 + tx] = tile[tx][ty + 8*i];
}

// ---------------- Flash attention (non-causal, GQA) ----------------
// grid (S/64, NH, B), 256 thr. Wave w owns q rows [qb*64+w*16, +16).
// Q pre-scaled by 1/sqrt(HD). K frags from global (L2-resident), V as vt[d][s].
__global__ __launch_bounds__(256) void k_flash(const bf16_t* __restrict__ qr,
                                               const bf16_t* __restrict__ kr,
                                               const bf16_t* __restrict__ vt,
                                               bf16_t* __restrict__ ctx) {
  __shared__ __align__(16) bf16_t plds[4][16][80];   // per-wave P scratch, padded
  const int tid = threadIdx.x;
  const int l = tid & 63, w = tid >> 6;
  const int lr = l & 15, lg = l >> 4;
  const int qb = blockIdx.x, h = blockIdx.y, b = blockIdx.z;
  const int kvh = h >> 2;   // NREP=4

  const bf16_t* qbase = qr + (((size_t)b * NH_ + h) * S_ + qb * 64 + w * 16) * HD_;
  const bf16_t* kbase = kr + (((size_t)b * NKV_ + kvh) * S_) * HD_;
  const bf16_t* vbase = vt + (((size_t)b * NKV_ + kvh) * HD_) * S_;

  bf16x8 qf[4];
#pragma unroll
  for (int kk = 0; kk < 4; kk++)
    qf[kk] = *(const bf16x8*)(qbase + lr * HD_ + kk * 32 + lg * 8);

  f32x4 o[8];
#pragma unroll
  for (int n = 0; n < 8; n++) o[n] = f32x4{0.f, 0.f, 0.f, 0.f};
  float mR[4] = {-1e30f, -1e30f, -1e30f, -1e30f};
  float lR[4] = {0.f, 0.f, 0.f, 0.f};

  for (int kb = 0; kb < S_; kb += 64) {
    f32x4 sc[4];
#pragma unroll
    for (int n = 0; n < 4; n++) {
      sc[n] = f32x4{0.f, 0.f, 0.f, 0.f};
#pragma unroll
      for (int kk = 0; kk < 4; kk++) {
        bf16x8 kf = *(const bf16x8*)(kbase + (size_t)(kb + n * 16 + lr) * HD_ + kk * 32 + lg * 8);
        sc[n] = __builtin_amdgcn_mfma_f32_16x16x32_bf16(qf[kk], kf, sc[n], 0, 0, 0);
      }
    }
    float tmax[4], alpha[4], psum[4];
#pragma unroll
    for (int i = 0; i < 4; i++) {
      float t = fmaxf(fmaxf(sc[0][i], sc[1][i]), fmaxf(sc[2][i], sc[3][i]));
      t = fmaxf(t, __shfl_xor(t, 1));
      t = fmaxf(t, __shfl_xor(t, 2));
      t = fmaxf(t, __shfl_xor(t, 4));
      t = fmaxf(t, __shfl_xor(t, 8));
      tmax[i] = t;
    }
#pragma unroll
    for (int i = 0; i < 4; i++) {
      float mnew = fmaxf(mR[i], tmax[i]);
      alpha[i] = __expf(mR[i] - mnew);
      mR[i] = mnew;
      psum[i] = 0.f;
    }
#pragma unroll
    for (int n = 0; n < 4; n++)
#pragma unroll
      for (int i = 0; i < 4; i++) {
        float pv = __expf(sc[n][i] - mR[i]);
        psum[i] += pv;
        plds[w][lg * 4 + i][n * 16 + lr] = (bf16_t)pv;
      }
#pragma unroll
    for (int i = 0; i < 4; i++) {
      float t = psum[i];
      t += __shfl_xor(t, 1);
      t += __shfl_xor(t, 2);
      t += __shfl_xor(t, 4);
      t += __shfl_xor(t, 8);
      lR[i] = lR[i] * alpha[i] + t;
    }
#pragma unroll
    for (int n = 0; n < 8; n++)
#pragma unroll
      for (int i = 0; i < 4; i++) o[n][i] *= alpha[i];
    // PV: A = P[16][64] from LDS, B = V^T fragments from global
#pragma unroll
    for (int kk = 0; kk < 2; kk++) {
      bf16x8 pf = *(const bf16x8*)(&plds[w][lr][kk * 32 + lg * 8]);
#pragma unroll
      for (int n = 0; n < 8; n++) {
        bf16x8 vf = *(const bf16x8*)(vbase + (size_t)(n * 16 + lr) * S_ + kb + kk * 32 + lg * 8);
        o[n] = __builtin_amdgcn_mfma_f32_16x16x32_bf16(pf, vf, o[n], 0, 0, 0);
      }
    }
  }

#pragma unroll
  for (int n = 0; n < 8; n++)
#pragma unroll
    for (int i = 0; i < 4; i++) {
      int srow = qb * 64 + w * 16 + lg * 4 + i;
      int d = n * 16 + lr;
      ctx[((size_t)(b * S_ + srow)) * D_ + h * HD_ + d] = (bf16_t)(o[n][i] / lR[i]);
    }
}

// ---------------- launch ----------------
extern "C" void kernel_launch(void* const* d_in, const int* in_sizes, int n_in,
                              void* d_out, int out_size, void* d_ws, size_t ws_size,
                              hipStream_t stream) {
  const float* x    = (const float*)d_in[0];
  const float* wq   = (const float*)d_in[1];
  const float* wk   = (const float*)d_in[2];
  const float* wv   = (const float*)d_in[3];
  const float* wo   = (const float*)d_in[4];
  const float* fcos = (const float*)d_in[5];
  const float* fsin = (const float*)d_in[6];
  float* out = (float*)d_out;

  // workspace layout (aliased; 160 MB total)
  const size_t SZ_XB    = (size_t)BS_ * D_ * 2;      // 32 MB  (xb, later qrope)
  const size_t SZ_WQKVT = (size_t)NQK_ * D_ * 2;     // 48 MB  (wqkvt, later krope+vtr)
  const size_t SZ_WOT   = (size_t)D_ * D_ * 2;       // 32 MB
  char* p = (char*)d_ws;
  bf16_t* xb    = (bf16_t*)p;                        // then qrope
  bf16_t* wqkvt = (bf16_t*)(p + SZ_XB);              // then krope, vtr
  bf16_t* wot   = (bf16_t*)(p + SZ_XB + SZ_WQKVT);
  bf16_t* qkv   = (bf16_t*)(p + SZ_XB + SZ_WQKVT + SZ_WOT);  // then ctx
  bf16_t* qrope = xb;
  bf16_t* krope = wqkvt;
  bf16_t* vtr   = wqkvt + (size_t)BS_ * NKV_ * HD_;
  bf16_t* ctx   = qkv;

  dim3 tb(32, 8);
  // 1. x -> bf16
  k_cvt<<<BS_ * D_ / 1024, 256, 0, stream>>>((const float4*)x, (bf16x4*)xb, BS_ * D_ / 4);
  // 2. transpose+convert weights (fused qkv weight, then wo)
  k_transpose_cvt<<<dim3(D_ / 32, D_ / 32), tb, 0, stream>>>(wq, wqkvt, D_, D_);
  k_transpose_cvt<<<dim3(32, D_ / 32), tb, 0, stream>>>(wk, wqkvt + (size_t)D_ * D_, D_, NKV_ * HD_);
  k_transpose_cvt<<<dim3(32, D_ / 32), tb, 0, stream>>>(wv, wqkvt + (size_t)(D_ + NKV_ * HD_) * D_, D_, NKV_ * HD_);
  k_transpose_cvt<<<dim3(D_ / 32, D_ / 32), tb, 0, stream>>>(wo, wot, D_, D_);
  // 3. fused QKV projection
  k_gemm_bt<bf16_t><<<dim3(NQK_ / 128, BS_ / 128), 256, 0, stream>>>(xb, wqkvt, qkv, BS_, NQK_, D_);
  // 4. RoPE + reorder (Q pre-scaled by 1/sqrt(HD)), V transpose
  k_rope<<<BS_ * NH_ * 64 / 256, 256, 0, stream>>>(qkv, fcos, fsin, qrope, NH_, 0, 0.08838834764831845f);
  k_rope<<<BS_ * NKV_ * 64 / 256, 256, 0, stream>>>(qkv, fcos, fsin, krope, NKV_, D_, 1.0f);
  k_vtrans<<<dim3(S_ / 32, HD_ / 32, B_ * NKV_), tb, 0, stream>>>(qkv, vtr);
  // 5. flash attention
  k_flash<<<dim3(S_ / 64, NH_, B_), 256, 0, stream>>>(qrope, krope, vtr, ctx);
  // 6. output projection -> f32 out
  k_gemm_bt<float><<<dim3(D_ / 128, BS_ / 128), 256, 0, stream>>>(ctx, wot, out, BS_, D_, D_);
}

// Round 2
// 806.648 us; speedup vs baseline: 1.8172x; 1.8172x over previous
//
#include <hip/hip_runtime.h>
#include <hip/hip_bf16.h>
#include <cstdint>

#define B_   2
#define S_   2048
#define D_   4096
#define NH_  32
#define NKV_ 8
#define HD_  128
#define BS_  (B_*S_)      // 4096 rows
#define NQK_ 6144         // NH*HD + 2*NKV*HD

typedef __bf16 bf16_t;
typedef __bf16 bf16x8 __attribute__((ext_vector_type(8)));
typedef __bf16 bf16x4 __attribute__((ext_vector_type(4)));
typedef __bf16 bf16x2 __attribute__((ext_vector_type(2)));
typedef float  f32x4  __attribute__((ext_vector_type(4)));

typedef const __attribute__((address_space(1))) void* gas_ptr;
typedef __attribute__((address_space(3))) void* las_ptr;

__device__ __forceinline__ void gload_lds16(const void* g, void* l) {
  __builtin_amdgcn_global_load_lds((gas_ptr)g, (las_ptr)l, 16, 0, 0);
}

// ---------------- f32 -> bf16 convert (vectorized) ----------------
__global__ __launch_bounds__(256) void k_cvt(const float4* __restrict__ in,
                                             bf16x4* __restrict__ out, int n4) {
  int i = blockIdx.x * 256 + threadIdx.x;
  if (i >= n4) return;
  float4 v = in[i];
  bf16x4 o = { (bf16_t)v.x, (bf16_t)v.y, (bf16_t)v.z, (bf16_t)v.w };
  out[i] = o;
}

// ---------------- w[K][N] f32 -> wt[N][K] bf16 (tiled transpose) ----------------
__global__ __launch_bounds__(256) void k_transpose_cvt(const float* __restrict__ w,
                                                       bf16_t* __restrict__ wt,
                                                       int K, int N) {
  __shared__ float tile[32][33];
  int n0 = blockIdx.x * 32, k0 = blockIdx.y * 32;
  int tx = threadIdx.x, ty = threadIdx.y;   // 32x8
#pragma unroll
  for (int i = 0; i < 4; i++)
    tile[ty + 8*i][tx] = w[(size_t)(k0 + ty + 8*i) * N + n0 + tx];
  __syncthreads();
#pragma unroll
  for (int i = 0; i < 4; i++)
    wt[(size_t)(n0 + ty + 8*i) * K + k0 + tx] = (bf16_t)tile[tx][ty + 8*i];
}

// ---------------- NT GEMM: C[M][N] = A[M][K] @ Bt[N][K]^T (bf16 in, CT out) -----
// m97 structure: 128x128 tile, BK=32, 4 waves (2x2), 4x4 16x16x32 frags/wave.
template <typename CT>
__global__ __launch_bounds__(256) void k_gemm_bt(const bf16_t* __restrict__ A,
                                                 const bf16_t* __restrict__ Bt,
                                                 CT* __restrict__ C,
                                                 int M, int N, int K) {
  __shared__ __align__(16) bf16_t As[128 * 32];
  __shared__ __align__(16) bf16_t Bs[128 * 32];
  const int tid = threadIdx.x;
  const int l = tid & 63, w = tid >> 6;
  const int lr = l & 15, lg = l >> 4;
  const int wm = w >> 1, wn = w & 1;
  const int bm = blockIdx.y, bn = blockIdx.x;

  const bf16_t* Ab = A  + (size_t)bm * 128 * K;
  const bf16_t* Bb = Bt + (size_t)bn * 128 * K;

  f32x4 acc[4][4];
#pragma unroll
  for (int m = 0; m < 4; m++)
#pragma unroll
    for (int n = 0; n < 4; n++) acc[m][n] = f32x4{0.f, 0.f, 0.f, 0.f};

  const int c0 = tid, c1 = 256 + tid;
  const int r0 = c0 >> 2, q0 = (c0 & 3) * 8;
  const int r1 = c1 >> 2, q1 = (c1 & 3) * 8;

  for (int kt = 0; kt < K; kt += 32) {
    gload_lds16(Ab + (size_t)r0 * K + kt + q0, As + c0 * 8);
    gload_lds16(Ab + (size_t)r1 * K + kt + q1, As + c1 * 8);
    gload_lds16(Bb + (size_t)r0 * K + kt + q0, Bs + c0 * 8);
    gload_lds16(Bb + (size_t)r1 * K + kt + q1, Bs + c1 * 8);
    __syncthreads();
    bf16x8 af[4], bfr[4];
#pragma unroll
    for (int m = 0; m < 4; m++)
      af[m] = *(const bf16x8*)(As + (wm * 64 + m * 16 + lr) * 32 + lg * 8);
#pragma unroll
    for (int n = 0; n < 4; n++)
      bfr[n] = *(const bf16x8*)(Bs + (wn * 64 + n * 16 + lr) * 32 + lg * 8);
#pragma unroll
    for (int m = 0; m < 4; m++)
#pragma unroll
      for (int n = 0; n < 4; n++)
        acc[m][n] = __builtin_amdgcn_mfma_f32_16x16x32_bf16(af[m], bfr[n], acc[m][n], 0, 0, 0);
    __syncthreads();
  }

#pragma unroll
  for (int m = 0; m < 4; m++) {
    int row0 = bm * 128 + wm * 64 + m * 16 + lg * 4;
#pragma unroll
    for (int n = 0; n < 4; n++) {
      int col = bn * 128 + wn * 64 + n * 16 + lr;
#pragma unroll
      for (int i = 0; i < 4; i++) {
        C[(size_t)(row0 + i) * N + col] = (CT)acc[m][n][i];
      }
    }
  }
}

// ---------------- RoPE + head-major reorder ----------------
__global__ __launch_bounds__(256) void k_rope(const bf16_t* __restrict__ qkv,
                                              const float* __restrict__ fcos,
                                              const float* __restrict__ fsin,
                                              bf16_t* __restrict__ dst,
                                              int nheads, int col_off, float mul) {
  int idx = blockIdx.x * 256 + threadIdx.x;   // B*S*nheads*64 threads
  int p = idx & 63;
  int h = (idx >> 6) % nheads;
  int bs = idx / (64 * nheads);
  int s = bs & (S_ - 1);
  int b = bs >> 11;                            // bs / S_
  const bf16_t* src = qkv + (size_t)bs * NQK_ + col_off + h * HD_ + 2 * p;
  bf16x2 ab = *(const bf16x2*)src;
  float a = (float)ab[0], bb = (float)ab[1];
  float c = fcos[s * 64 + p], sn = fsin[s * 64 + p];
  bf16x2 o = { (bf16_t)((a * c - bb * sn) * mul), (bf16_t)((a * sn + bb * c) * mul) };
  *(bf16x2*)(dst + ((((size_t)b * nheads + h) * S_ + s) * HD_) + 2 * p) = o;
}

// ---------------- V transpose: qkv v-cols -> vt[B][NKV][HD][S] ----------------
__global__ __launch_bounds__(256) void k_vtrans(const bf16_t* __restrict__ qkv,
                                                bf16_t* __restrict__ vtr) {
  __shared__ bf16_t tile[32][33];
  int s0 = blockIdx.x * 32, d0 = blockIdx.y * 32, z = blockIdx.z;  // z = b*NKV+kvh
  int b = z >> 3, kvh = z & 7;
  int tx = threadIdx.x, ty = threadIdx.y;
#pragma unroll
  for (int i = 0; i < 4; i++)
    tile[ty + 8*i][tx] =
        qkv[(size_t)(b * S_ + s0 + ty + 8*i) * NQK_ + (D_ + NKV_ * HD_) + kvh * HD_ + d0 + tx];
  __syncthreads();
#pragma unroll
  for (int i = 0; i < 4; i++)
    vtr[((size_t)z * HD_ + d0 + ty + 8*i) * S_ + s0 + tx] = tile[tx][ty + 8*i];
}

// ---------------- Flash attention (non-causal, GQA) ----------------
// grid (S/128, NH, B), 256 thr (4 waves). Wave w owns q rows [qb*128+w*32, +32)
// as two 16-row m-frags. K/V tiles (KVBLK=64) staged in LDS, double-buffered,
// XOR-swizzled (pre-swizzled global source, linear LDS dest per m173/rule21).
#define KVBLK 64
__global__ __launch_bounds__(256, 2) void k_flash(const bf16_t* __restrict__ qr,
                                                  const bf16_t* __restrict__ kr,
                                                  const bf16_t* __restrict__ vt,
                                                  bf16_t* __restrict__ ctx) {
  __shared__ __align__(16) bf16_t Ks[2][KVBLK * HD_];   // 2 x 16 KB [row s][col d]
  __shared__ __align__(16) bf16_t Vs[2][HD_ * KVBLK];   // 2 x 16 KB [row d][col s]
  __shared__ __align__(16) bf16_t plds[4][16][72];      // per-wave P scratch
  const int tid = threadIdx.x;
  const int l = tid & 63, w = tid >> 6;
  const int lr = l & 15, lg = l >> 4;
  const int qb = blockIdx.x, h = blockIdx.y, b = blockIdx.z;
  const int kvh = h >> 2;   // NREP=4

  const bf16_t* qbase = qr + (((size_t)b * NH_ + h) * S_ + qb * 128 + w * 32) * HD_;
  const bf16_t* kbase = kr + (((size_t)b * NKV_ + kvh) * S_) * HD_;
  const bf16_t* vbase = vt + (((size_t)b * NKV_ + kvh) * HD_) * S_;

  // Q fragments (pre-scaled by 1/sqrt(HD) in k_rope)
  bf16x8 qf[2][4];
#pragma unroll
  for (int m = 0; m < 2; m++)
#pragma unroll
    for (int kk = 0; kk < 4; kk++)
      qf[m][kk] = *(const bf16x8*)(qbase + (m * 16 + lr) * HD_ + kk * 32 + lg * 8);

  f32x4 o[2][8];
#pragma unroll
  for (int m = 0; m < 2; m++)
#pragma unroll
    for (int n = 0; n < 8; n++) o[m][n] = f32x4{0.f, 0.f, 0.f, 0.f};
  float mR[2][4], lR[2][4];
#pragma unroll
  for (int m = 0; m < 2; m++)
#pragma unroll
    for (int i = 0; i < 4; i++) { mR[m][i] = -1e30f; lR[m][i] = 0.f; }

  // stage tile t into buffer bu (K: 16KB, V: 16KB; 8 gload16/thread)
  auto stage = [&](int bu, int t) {
    const int kb = t * KVBLK;
#pragma unroll
    for (int j = 0; j < 4; j++) {
      int o_ = (tid + 256 * j) * 16;                 // byte offset in K tile
      int row = o_ >> 8, cb = o_ & 255;              // row stride 256B
      int scb = cb ^ ((row & 7) << 4);
      gload_lds16(kbase + (size_t)(kb + row) * HD_ + (scb >> 1),
                  &Ks[bu][0] + (o_ >> 1));
    }
#pragma unroll
    for (int j = 0; j < 4; j++) {
      int o_ = (tid + 256 * j) * 16;                 // byte offset in V tile
      int row = o_ >> 7, cb = o_ & 127;              // row stride 128B
      int scb = cb ^ ((row & 7) << 4);
      gload_lds16(vbase + (size_t)row * S_ + kb + (scb >> 1),
                  &Vs[bu][0] + (o_ >> 1));
    }
  };

  const int nt = S_ / KVBLK;
  stage(0, 0);
  __syncthreads();
  int buf = 0;

  for (int t = 0; t < nt; t++) {
    if (t + 1 < nt) stage(buf ^ 1, t + 1);
    const bf16_t* Kb = &Ks[buf][0];
    const bf16_t* Vb = &Vs[buf][0];

    // QK^T: sc[m][n], K frag shared across m
    f32x4 sc[2][4];
#pragma unroll
    for (int m = 0; m < 2; m++)
#pragma unroll
      for (int n = 0; n < 4; n++) sc[m][n] = f32x4{0.f, 0.f, 0.f, 0.f};
#pragma unroll
    for (int n = 0; n < 4; n++) {
#pragma unroll
      for (int kk = 0; kk < 4; kk++) {
        int r = n * 16 + lr;
        int cb = (kk * 64 + lg * 16) ^ ((r & 7) << 4);
        bf16x8 kf = *(const bf16x8*)(Kb + (((r << 8) + cb) >> 1));
        sc[0][n] = __builtin_amdgcn_mfma_f32_16x16x32_bf16(qf[0][kk], kf, sc[0][n], 0, 0, 0);
        sc[1][n] = __builtin_amdgcn_mfma_f32_16x16x32_bf16(qf[1][kk], kf, sc[1][n], 0, 0, 0);
      }
    }

    // online softmax per m-frag; P staged via per-wave LDS, read back to regs
    bf16x8 pf[2][2];
#pragma unroll
    for (int m = 0; m < 2; m++) {
      float alpha[4], psum[4];
#pragma unroll
      for (int i = 0; i < 4; i++) {
        float tmx = fmaxf(fmaxf(sc[m][0][i], sc[m][1][i]),
                          fmaxf(sc[m][2][i], sc[m][3][i]));
        tmx = fmaxf(tmx, __shfl_xor(tmx, 1));
        tmx = fmaxf(tmx, __shfl_xor(tmx, 2));
        tmx = fmaxf(tmx, __shfl_xor(tmx, 4));
        tmx = fmaxf(tmx, __shfl_xor(tmx, 8));
        float mnew = fmaxf(mR[m][i], tmx);
        alpha[i] = __expf(mR[m][i] - mnew);
        mR[m][i] = mnew;
        psum[i] = 0.f;
      }
#pragma unroll
      for (int n = 0; n < 4; n++)
#pragma unroll
        for (int i = 0; i < 4; i++) {
          float pv = __expf(sc[m][n][i] - mR[m][i]);
          psum[i] += pv;
          plds[w][lg * 4 + i][n * 16 + lr] = (bf16_t)pv;
        }
#pragma unroll
      for (int i = 0; i < 4; i++) {
        float t2 = psum[i];
        t2 += __shfl_xor(t2, 1);
        t2 += __shfl_xor(t2, 2);
        t2 += __shfl_xor(t2, 4);
        t2 += __shfl_xor(t2, 8);
        lR[m][i] = lR[m][i] * alpha[i] + t2;
      }
#pragma unroll
      for (int n = 0; n < 8; n++)
#pragma unroll
        for (int i = 0; i < 4; i++) o[m][n][i] *= alpha[i];
      pf[m][0] = *(const bf16x8*)(&plds[w][lr][lg * 8]);
      pf[m][1] = *(const bf16x8*)(&plds[w][lr][32 + lg * 8]);
    }

    // PV: V frag loaded once, shared across both m
#pragma unroll
    for (int n = 0; n < 8; n++) {
#pragma unroll
      for (int kk = 0; kk < 2; kk++) {
        int r = n * 16 + lr;
        int cb = (kk * 64 + lg * 16) ^ ((r & 7) << 4);
        bf16x8 vf = *(const bf16x8*)(Vb + (((r << 7) + cb) >> 1));
        o[0][n] = __builtin_amdgcn_mfma_f32_16x16x32_bf16(pf[0][kk], vf, o[0][n], 0, 0, 0);
        o[1][n] = __builtin_amdgcn_mfma_f32_16x16x32_bf16(pf[1][kk], vf, o[1][n], 0, 0, 0);
      }
    }
    __syncthreads();
    buf ^= 1;
  }

#pragma unroll
  for (int m = 0; m < 2; m++)
#pragma unroll
    for (int n = 0; n < 8; n++)
#pragma unroll
      for (int i = 0; i < 4; i++) {
        int srow = qb * 128 + w * 32 + m * 16 + lg * 4 + i;
        int d = n * 16 + lr;
        ctx[((size_t)(b * S_ + srow)) * D_ + h * HD_ + d] = (bf16_t)(o[m][n][i] / lR[m][i]);
      }
}

// ---------------- launch ----------------
extern "C" void kernel_launch(void* const* d_in, const int* in_sizes, int n_in,
                              void* d_out, int out_size, void* d_ws, size_t ws_size,
                              hipStream_t stream) {
  const float* x    = (const float*)d_in[0];
  const float* wq   = (const float*)d_in[1];
  const float* wk   = (const float*)d_in[2];
  const float* wv   = (const float*)d_in[3];
  const float* wo   = (const float*)d_in[4];
  const float* fcos = (const float*)d_in[5];
  const float* fsin = (const float*)d_in[6];
  float* out = (float*)d_out;

  // workspace layout (aliased; 160 MB total)
  const size_t SZ_XB    = (size_t)BS_ * D_ * 2;      // 32 MB  (xb, later qrope)
  const size_t SZ_WQKVT = (size_t)NQK_ * D_ * 2;     // 48 MB  (wqkvt, later krope+vtr)
  const size_t SZ_WOT   = (size_t)D_ * D_ * 2;       // 32 MB
  char* p = (char*)d_ws;
  bf16_t* xb    = (bf16_t*)p;                        // then qrope
  bf16_t* wqkvt = (bf16_t*)(p + SZ_XB);              // then krope, vtr
  bf16_t* wot   = (bf16_t*)(p + SZ_XB + SZ_WQKVT);
  bf16_t* qkv   = (bf16_t*)(p + SZ_XB + SZ_WQKVT + SZ_WOT);  // then ctx
  bf16_t* qrope = xb;
  bf16_t* krope = wqkvt;
  bf16_t* vtr   = wqkvt + (size_t)BS_ * NKV_ * HD_;
  bf16_t* ctx   = qkv;

  dim3 tb(32, 8);
  // 1. x -> bf16
  k_cvt<<<BS_ * D_ / 1024, 256, 0, stream>>>((const float4*)x, (bf16x4*)xb, BS_ * D_ / 4);
  // 2. transpose+convert weights (fused qkv weight, then wo)
  k_transpose_cvt<<<dim3(D_ / 32, D_ / 32), tb, 0, stream>>>(wq, wqkvt, D_, D_);
  k_transpose_cvt<<<dim3(32, D_ / 32), tb, 0, stream>>>(wk, wqkvt + (size_t)D_ * D_, D_, NKV_ * HD_);
  k_transpose_cvt<<<dim3(32, D_ / 32), tb, 0, stream>>>(wv, wqkvt + (size_t)(D_ + NKV_ * HD_) * D_, D_, NKV_ * HD_);
  k_transpose_cvt<<<dim3(D_ / 32, D_ / 32), tb, 0, stream>>>(wo, wot, D_, D_);
  // 3. fused QKV projection
  k_gemm_bt<bf16_t><<<dim3(NQK_ / 128, BS_ / 128), 256, 0, stream>>>(xb, wqkvt, qkv, BS_, NQK_, D_);
  // 4. RoPE + reorder (Q pre-scaled by 1/sqrt(HD)), V transpose
  k_rope<<<BS_ * NH_ * 64 / 256, 256, 0, stream>>>(qkv, fcos, fsin, qrope, NH_, 0, 0.08838834764831845f);
  k_rope<<<BS_ * NKV_ * 64 / 256, 256, 0, stream>>>(qkv, fcos, fsin, krope, NKV_, D_, 1.0f);
  k_vtrans<<<dim3(S_ / 32, HD_ / 32, B_ * NKV_), tb, 0, stream>>>(qkv, vtr);
  // 5. flash attention
  k_flash<<<dim3(S_ / 128, NH_, B_), 256, 0, stream>>>(qrope, krope, vtr, ctx);
  // 6. output projection -> f32 out
  k_gemm_bt<float><<<dim3(D_ / 128, BS_ / 128), 256, 0, stream>>>(ctx, wot, out, BS_, D_, D_);
}